// Round 7
// baseline (133.500 us; speedup 1.0000x reference)
//
#include <hip/hip_runtime.h>
#include <hip/hip_fp16.h>
#include <hip/hip_bf16.h>
#include <math.h>

#define D 128
#define LDAP 136   // padded LDS row length (bf16 elems)

typedef unsigned int   u32;
typedef unsigned short u16;
using f32x4 = __attribute__((ext_vector_type(4))) float;
using s16x8 = __attribute__((ext_vector_type(8))) short;
using u32x4 = __attribute__((ext_vector_type(4))) unsigned int;

__device__ __forceinline__ u16 f2bf(float f) {       // RNE f32->bf16
    u32 u = __float_as_uint(f);
    return (u16)((u + 0x7FFFu + ((u >> 16) & 1u)) >> 16);
}

// ---------------------------------------------------------------------------
// Per-wave int64-vs-int32 edge_index detection (high words of first 64
// elements all zero => int64). Deterministic, same answer in every block.
// ---------------------------------------------------------------------------
__device__ __forceinline__ bool detect_is64(const int* __restrict__ idx32, int E) {
    int lane = threadIdx.x & 63;
    int hi = 0;
    if (lane < E) hi = idx32[2 * lane + 1];
    return __ballot(hi != 0) == 0ull;
}

// ---------------------------------------------------------------------------
// prep+zero: blocks 0..127 transpose W1_top/W2 to bf16; block 128 builds
// w_vec/c_vec; blocks 129.. zero the counts array (u32x4 granularity).
// ---------------------------------------------------------------------------
__global__ __launch_bounds__(128) void prep_zero_kernel(
    const float* __restrict__ W_edge, const float* __restrict__ b_edge,
    const float* __restrict__ W1, const float* __restrict__ b1,
    const float* __restrict__ W2, float* __restrict__ wc,
    u16* __restrict__ Wt1, u16* __restrict__ Wt2,
    u32x4* __restrict__ counts4, int nz4)
{
    const int b = blockIdx.x, t = threadIdx.x;
    if (b < D) {
        Wt1[b * D + t] = f2bf(W1[(size_t)t * D + b]);
        Wt2[b * D + t] = f2bf(W2[(size_t)t * D + b]);
    } else if (b == D) {
        float w = 0.f, c = 0.f;
        #pragma unroll 8
        for (int k = 0; k < D; ++k) {
            float w1 = W1[(size_t)(D + k) * D + t];
            w = fmaf(W_edge[k], w1, w);
            c = fmaf(b_edge[k], w1, c);
        }
        wc[t]     = w;
        wc[D + t] = c + b1[t];
    } else {
        int i = (b - D - 1) * 128 + t;
        if (i < nz4) counts4[i] = (u32x4){0u, 0u, 0u, 0u};
    }
}

// ---------------------------------------------------------------------------
// count: rows only. atomicAdd returns within-row sequence number;
// store rowseq = row<<16|seq coalesced (nt). (N < 65536, deg < 65536.)
// ---------------------------------------------------------------------------
__global__ __launch_bounds__(256) void count_kernel(
    const void* __restrict__ eidx, u32* __restrict__ counts,
    u32* __restrict__ rowseq, int E)
{
    const bool is64 = detect_is64((const int*)eidx, E);
    const long long* e64 = (const long long*)eidx;
    const int*       e32 = (const int*)eidx;
    const int tid = blockIdx.x * blockDim.x + threadIdx.x;
    const int e4  = E & ~3;
    const int e0  = tid * 4;

    if (e0 < e4) {
        int rows[4];
        if (is64) {
            #pragma unroll
            for (int j = 0; j < 4; ++j) rows[j] = (int)e64[e0 + j];
        } else {
            #pragma unroll
            for (int j = 0; j < 4; ++j) rows[j] = e32[e0 + j];
        }
        u32x4 rs;
        #pragma unroll
        for (int j = 0; j < 4; ++j) {
            u32 seq = atomicAdd(&counts[rows[j]], 1u);
            rs[j] = ((u32)rows[j] << 16) | (seq & 0xFFFFu);
        }
        __builtin_nontemporal_store(rs, (u32x4*)&rowseq[e0]);
    }
    if (tid < E - e4) {
        int e = e4 + tid;
        int row = is64 ? (int)e64[e] : e32[e];
        u32 seq = atomicAdd(&counts[row], 1u);
        rowseq[e] = ((u32)row << 16) | (seq & 0xFFFFu);
    }
}

// ---------------------------------------------------------------------------
// exclusive scan (N <= 65536)
// ---------------------------------------------------------------------------
__global__ __launch_bounds__(256) void scanA_kernel(
    const u32* __restrict__ counts, u32* __restrict__ chunkSum, int N)
{
    __shared__ u32 s[256];
    int t = threadIdx.x, i = blockIdx.x * 256 + t;
    s[t] = (i < N) ? counts[i] : 0u;
    __syncthreads();
    for (int off = 128; off > 0; off >>= 1) {
        if (t < off) s[t] += s[t + off];
        __syncthreads();
    }
    if (t == 0) chunkSum[blockIdx.x] = s[0];
}

__global__ __launch_bounds__(256) void scanB_kernel(
    const u32* __restrict__ chunkSum, u32* __restrict__ chunkBase,
    u32* __restrict__ offsets, int NCH, int N)
{
    __shared__ u32 s[256];
    int t = threadIdx.x;
    u32 v = (t < NCH) ? chunkSum[t] : 0u;
    s[t] = v;
    __syncthreads();
    for (int off = 1; off < 256; off <<= 1) {
        u32 a = (t >= off) ? s[t - off] : 0u;
        __syncthreads();
        s[t] += a;
        __syncthreads();
    }
    if (t < NCH) chunkBase[t] = s[t] - v;
    if (t == 255) offsets[N] = s[255];
}

__global__ __launch_bounds__(256) void scanC_kernel(
    const u32* __restrict__ counts, const u32* __restrict__ chunkBase,
    u32* __restrict__ offsets, int N)
{
    __shared__ u32 s[256];
    int t = threadIdx.x, i = blockIdx.x * 256 + t;
    u32 v = (i < N) ? counts[i] : 0u;
    s[t] = v;
    __syncthreads();
    for (int off = 1; off < 256; off <<= 1) {
        u32 a = (t >= off) ? s[t - off] : 0u;
        __syncthreads();
        s[t] += a;
        __syncthreads();
    }
    if (i < N) offsets[i] = s[t] - v + chunkBase[blockIdx.x];
}

// ---------------------------------------------------------------------------
// scatter: cols + dist computed here (row comes from rowseq high bits).
// pos = offsets[row] + seq; packed[pos] = col | f16(dist)<<16. No atomics.
// ---------------------------------------------------------------------------
__global__ __launch_bounds__(256) void scatter_kernel(
    const void* __restrict__ eidx, const float* __restrict__ coord,
    const u32* __restrict__ rowseq, const u32* __restrict__ offsets,
    u32* __restrict__ packed, int E)
{
    const bool is64 = detect_is64((const int*)eidx, E);
    const long long* e64 = (const long long*)eidx;
    const int*       e32 = (const int*)eidx;
    const int tid = blockIdx.x * blockDim.x + threadIdx.x;
    const int e4  = E & ~3;
    const int e0  = tid * 4;

    if (e0 < e4) {
        u32x4 rs = *(const u32x4*)&rowseq[e0];
        int cols[4];
        if (is64) {
            #pragma unroll
            for (int j = 0; j < 4; ++j) cols[j] = (int)e64[E + e0 + j];
        } else {
            #pragma unroll
            for (int j = 0; j < 4; ++j) cols[j] = e32[E + e0 + j];
        }
        #pragma unroll
        for (int j = 0; j < 4; ++j) {
            u32 r  = rs[j];
            int row = (int)(r >> 16);
            float dx = coord[3 * row + 0] - coord[3 * cols[j] + 0];
            float dy = coord[3 * row + 1] - coord[3 * cols[j] + 1];
            float dz = coord[3 * row + 2] - coord[3 * cols[j] + 2];
            float dist = sqrtf(fmaf(dx, dx, fmaf(dy, dy, dz * dz)));
            u32 pos = offsets[row] + (r & 0xFFFFu);
            u32 rec = (u32)cols[j] |
                      ((u32)__half_as_ushort(__float2half(dist)) << 16);
            __builtin_nontemporal_store(rec, &packed[pos]);
        }
    }
    if (tid < E - e4) {
        int e = e4 + tid;
        u32 r = rowseq[e];
        int row = (int)(r >> 16);
        int col = is64 ? (int)e64[E + e] : e32[E + e];
        float dx = coord[3 * row + 0] - coord[3 * col + 0];
        float dy = coord[3 * row + 1] - coord[3 * col + 1];
        float dz = coord[3 * row + 2] - coord[3 * col + 2];
        float dist = sqrtf(fmaf(dx, dx, fmaf(dy, dy, dz * dz)));
        packed[offsets[row] + (r & 0xFFFFu)] =
            (u32)col | ((u32)__half_as_ushort(__float2half(dist)) << 16);
    }
}

// ---------------------------------------------------------------------------
// GEMM1: y = bf16(x @ W1_top). 4 waves, 64 rows/block, MFMA 16x16x32 bf16.
// ---------------------------------------------------------------------------
__global__ __launch_bounds__(256) void gemm1_kernel(
    const float* __restrict__ A, const u16* __restrict__ Wt,
    u16* __restrict__ out, int N)
{
    __shared__ u16 wl[D * LDAP];
    __shared__ u16 al[64 * LDAP];
    const int t    = threadIdx.x;
    const int lane = t & 63;
    const int w    = t >> 6;
    const int n0   = blockIdx.x * 64;

    #pragma unroll
    for (int i = 0; i < 8; ++i) {
        int e = (i * 256 + t) * 8;
        int r = e >> 7, c = e & 127;
        *(u32x4*)&wl[r * LDAP + c] = *(const u32x4*)&Wt[r * D + c];
    }
    #pragma unroll
    for (int i = 0; i < 8; ++i) {
        int idx = i * 256 + t;
        int r = idx >> 5, c4 = idx & 31;
        int gr = n0 + r; if (gr >= N) gr = N - 1;
        float4 v = *(const float4*)&A[(size_t)gr * D + c4 * 4];
        u32 lo = (u32)f2bf(v.x) | ((u32)f2bf(v.y) << 16);
        u32 hi = (u32)f2bf(v.z) | ((u32)f2bf(v.w) << 16);
        *(uint2*)&al[r * LDAP + c4 * 4] = make_uint2(lo, hi);
    }
    __syncthreads();

    const int  fr     = lane & 15;
    const int  kg     = lane >> 4;
    const bool wvalid = (n0 + w * 16) < N;

    f32x4 acc[8];
    #pragma unroll
    for (int i = 0; i < 8; ++i) acc[i] = (f32x4){0.f, 0.f, 0.f, 0.f};

    #pragma unroll
    for (int kk = 0; kk < 4; ++kk) {
        const int ko = kk * 32 + kg * 8;
        s16x8 a = *(const s16x8*)&al[(w * 16 + fr) * LDAP + ko];
        #pragma unroll
        for (int ct = 0; ct < 8; ++ct) {
            s16x8 b = *(const s16x8*)&wl[(ct * 16 + fr) * LDAP + ko];
            acc[ct] = __builtin_amdgcn_mfma_f32_16x16x32_bf16(a, b, acc[ct], 0, 0, 0);
        }
    }
    if (!wvalid) return;

    #pragma unroll
    for (int ct = 0; ct < 8; ++ct) {
        const int c = ct * 16 + fr;
        #pragma unroll
        for (int j = 0; j < 4; ++j) {
            int R = n0 + w * 16 + 4 * kg + j;
            out[(size_t)R * D + c] = f2bf(acc[ct][j]);
        }
    }
}

// ---------------------------------------------------------------------------
// Fused aggregate + GEMM2. 512 threads (8 waves), 64 rows/block.
// Phase A: stage Wt2 in LDS. Phase B: each wave pull-aggregates 8 rows
// (masked 8-deep gather loop) and writes bf16 H rows straight into the LDS
// A-tile. Phase C: MFMA H@W2; wave w does row-tile (w>>1), col-half (w&1).
// Epilogue: out = acc + x + deg*b2 (nt stores, never re-read).
// ---------------------------------------------------------------------------
__global__ __launch_bounds__(512) void agg_gemm2_kernel(
    const u16* __restrict__ ybf, const u32* __restrict__ offsets,
    const u32* __restrict__ packed, const float* __restrict__ wc,
    const u16* __restrict__ Wt2, const float* __restrict__ xres,
    const u32* __restrict__ degi, const float* __restrict__ bvec,
    float* __restrict__ out, int N)
{
    __shared__ u16 wl[D * LDAP];
    __shared__ u16 al[64 * LDAP];
    const int t    = threadIdx.x;
    const int lane = t & 63;
    const int w    = t >> 6;
    const int n0   = blockIdx.x * 64;

    #pragma unroll
    for (int i = 0; i < 4; ++i) {
        int e = (i * 512 + t) * 8;
        int r = e >> 7, c = e & 127;
        *(u32x4*)&wl[r * LDAP + c] = *(const u32x4*)&Wt2[r * D + c];
    }

    const float2 wv = ((const float2*)wc)[lane];
    const float2 cv = ((const float2*)(wc + D))[lane];

    for (int rr = 0; rr < 8; ++rr) {
        const int row = n0 + w * 8 + rr;
        float r0 = 0.f, r1 = 0.f;
        if (row < N) {
            const u32 beg = offsets[row], end = offsets[row + 1];
            float a0[4] = {0.f, 0.f, 0.f, 0.f};
            float a1[4] = {0.f, 0.f, 0.f, 0.f};
            for (u32 base = beg; base < end; base += 8) {
                u32 p[8], yv[8];
                #pragma unroll
                for (int j = 0; j < 8; ++j) {
                    u32 ee = base + j;
                    p[j] = packed[ee < end ? ee : end - 1];
                }
                #pragma unroll
                for (int j = 0; j < 8; ++j)
                    yv[j] = *(const u32*)(ybf + (size_t)(p[j] & 0xFFFFu) * D + 2 * lane);
                #pragma unroll
                for (int j = 0; j < 8; ++j) {
                    float dt = __half2float(__ushort_as_half((u16)(p[j] >> 16)));
                    float v0 = fmaxf(0.f, fmaf(dt, wv.x, __uint_as_float(yv[j] << 16)         + cv.x));
                    float v1 = fmaxf(0.f, fmaf(dt, wv.y, __uint_as_float(yv[j] & 0xFFFF0000u) + cv.y));
                    bool ok = (base + j) < end;
                    a0[j & 3] += ok ? v0 : 0.f;
                    a1[j & 3] += ok ? v1 : 0.f;
                }
            }
            r0 = (a0[0] + a0[1]) + (a0[2] + a0[3]);
            r1 = (a1[0] + a1[1]) + (a1[2] + a1[3]);
        }
        *(u32*)&al[(w * 8 + rr) * LDAP + 2 * lane] =
            (u32)f2bf(r0) | ((u32)f2bf(r1) << 16);
    }
    __syncthreads();

    const int fr = lane & 15;
    const int kg = lane >> 4;
    const int tr = w >> 1;               // 16-row tile index (0..3)
    const int ch = w & 1;                // column half (0..1)
    const bool tvalid = (n0 + tr * 16) < N;   // 16 | N -> tile-uniform

    f32x4 acc[4];
    #pragma unroll
    for (int i = 0; i < 4; ++i) acc[i] = (f32x4){0.f, 0.f, 0.f, 0.f};

    #pragma unroll
    for (int kk = 0; kk < 4; ++kk) {
        const int ko = kk * 32 + kg * 8;
        s16x8 a = *(const s16x8*)&al[(tr * 16 + fr) * LDAP + ko];
        #pragma unroll
        for (int ct = 0; ct < 4; ++ct) {
            s16x8 b = *(const s16x8*)&wl[((ch * 4 + ct) * 16 + fr) * LDAP + ko];
            acc[ct] = __builtin_amdgcn_mfma_f32_16x16x32_bf16(a, b, acc[ct], 0, 0, 0);
        }
    }
    if (!tvalid) return;

    float degf[4];
    #pragma unroll
    for (int j = 0; j < 4; ++j)
        degf[j] = (float)degi[n0 + tr * 16 + 4 * kg + j];

    #pragma unroll
    for (int ct = 0; ct < 4; ++ct) {
        const int c  = (ch * 4 + ct) * 16 + fr;
        const float bv = bvec[c];
        #pragma unroll
        for (int j = 0; j < 4; ++j) {
            int R = n0 + tr * 16 + 4 * kg + j;
            float r = acc[ct][j] + xres[(size_t)R * D + c] + degf[j] * bv;
            __builtin_nontemporal_store(r, &out[(size_t)R * D + c]);
        }
    }
}

// ---------------------------------------------------------------------------
extern "C" void kernel_launch(void* const* d_in, const int* in_sizes, int n_in,
                              void* d_out, int out_size, void* d_ws, size_t ws_size,
                              hipStream_t stream)
{
    const float* x      = (const float*)d_in[0];
    const float* coord  = (const float*)d_in[1];
    const void*  eidx   = d_in[2];
    const float* W_edge = (const float*)d_in[3];
    const float* b_edge = (const float*)d_in[4];
    const float* W1     = (const float*)d_in[5];
    const float* b1     = (const float*)d_in[6];
    const float* W2     = (const float*)d_in[7];
    const float* b2     = (const float*)d_in[8];

    const int N   = in_sizes[1] / 3;
    const int E   = in_sizes[2] / 2;
    const int EA  = (E + 3) & ~3;
    const int NCH = (N + 255) / 256;

    // ---- d_ws layout, every segment 256B-aligned (total ~18.5 MB; R1
    //      proved ws >= 25.8 MB). d_out is written only by the final kernel.
    #define ALN(x) (((size_t)(x) + 255) & ~(size_t)255)
    char*  wsb       = (char*)d_ws;
    size_t o         = 0;
    u16*   ybf       = (u16*)(wsb + o);  o += ALN((size_t)N * D * 2);
    u32*   rowseq    = (u32*)(wsb + o);  o += ALN((size_t)EA * 4);
    u32*   packed    = (u32*)(wsb + o);  o += ALN((size_t)EA * 4);
    u32*   offsets   = (u32*)(wsb + o);  o += ALN((size_t)(N + 1) * 4);
    u32*   counts    = (u32*)(wsb + o);  o += ALN((size_t)(N + 16) * 4);
    u32*   chunkSum  = (u32*)(wsb + o);  o += ALN((size_t)NCH * 4);
    u32*   chunkBase = (u32*)(wsb + o);  o += ALN((size_t)NCH * 4);
    float* wc        = (float*)(wsb + o); o += ALN(2 * D * 4);
    u16*   Wt1       = (u16*)(wsb + o);  o += ALN(D * D * 2);
    u16*   Wt2       = (u16*)(wsb + o);
    #undef ALN

    const int nz4 = (N + 16 + 3) / 4;
    const int ZB  = (nz4 + 127) / 128;
    prep_zero_kernel<<<D + 1 + ZB, 128, 0, stream>>>(
        W_edge, b_edge, W1, b1, W2, wc, Wt1, Wt2, (u32x4*)counts, nz4);

    const int CB = (E / 4 + 255) / 256;
    count_kernel<<<CB, 256, 0, stream>>>(eidx, counts, rowseq, E);
    scanA_kernel<<<NCH, 256, 0, stream>>>(counts, chunkSum, N);
    scanB_kernel<<<1, 256, 0, stream>>>(chunkSum, chunkBase, offsets, NCH, N);
    scanC_kernel<<<NCH, 256, 0, stream>>>(counts, chunkBase, offsets, N);
    scatter_kernel<<<CB, 256, 0, stream>>>(eidx, coord, rowseq, offsets,
                                           packed, E);

    const int GB = (N + 63) / 64;
    gemm1_kernel<<<GB, 256, 0, stream>>>(x, Wt1, ybf, N);

    agg_gemm2_kernel<<<GB, 512, 0, stream>>>(
        ybf, offsets, packed, wc, Wt2, x, counts, b2, (float*)d_out, N);
}

// Round 8
// 128.364 us; speedup vs baseline: 1.0400x; 1.0400x over previous
//
#include <hip/hip_runtime.h>
#include <hip/hip_fp16.h>
#include <hip/hip_bf16.h>
#include <math.h>

#define D 128
#define LDAP 136   // padded LDS row length (bf16 elems)

typedef unsigned int   u32;
typedef unsigned short u16;
using f32x4 = __attribute__((ext_vector_type(4))) float;
using s16x8 = __attribute__((ext_vector_type(8))) short;
using u32x4 = __attribute__((ext_vector_type(4))) unsigned int;

__device__ __forceinline__ u16 f2bf(float f) {       // RNE f32->bf16
    u32 u = __float_as_uint(f);
    return (u16)((u + 0x7FFFu + ((u >> 16) & 1u)) >> 16);
}

// ---------------------------------------------------------------------------
// Per-wave int64-vs-int32 edge_index detection (high words of first 64
// elements all zero => int64). Deterministic, same answer in every block.
// ---------------------------------------------------------------------------
__device__ __forceinline__ bool detect_is64(const int* __restrict__ idx32, int E) {
    int lane = threadIdx.x & 63;
    int hi = 0;
    if (lane < E) hi = idx32[2 * lane + 1];
    return __ballot(hi != 0) == 0ull;
}

// ---------------------------------------------------------------------------
// prep+zero: blocks 0..127 transpose W1_top/W2 to bf16; block 128 builds
// w_vec/c_vec; blocks 129.. zero the counts array (u32x4 granularity).
// ---------------------------------------------------------------------------
__global__ __launch_bounds__(128) void prep_zero_kernel(
    const float* __restrict__ W_edge, const float* __restrict__ b_edge,
    const float* __restrict__ W1, const float* __restrict__ b1,
    const float* __restrict__ W2, float* __restrict__ wc,
    u16* __restrict__ Wt1, u16* __restrict__ Wt2,
    u32x4* __restrict__ counts4, int nz4)
{
    const int b = blockIdx.x, t = threadIdx.x;
    if (b < D) {
        Wt1[b * D + t] = f2bf(W1[(size_t)t * D + b]);
        Wt2[b * D + t] = f2bf(W2[(size_t)t * D + b]);
    } else if (b == D) {
        float w = 0.f, c = 0.f;
        #pragma unroll 8
        for (int k = 0; k < D; ++k) {
            float w1 = W1[(size_t)(D + k) * D + t];
            w = fmaf(W_edge[k], w1, w);
            c = fmaf(b_edge[k], w1, c);
        }
        wc[t]     = w;
        wc[D + t] = c + b1[t];
    } else {
        int i = (b - D - 1) * 128 + t;
        if (i < nz4) counts4[i] = (u32x4){0u, 0u, 0u, 0u};
    }
}

// ---------------------------------------------------------------------------
// count: 4 edges/thread. atomicAdd returns the within-row sequence number;
// store rowseq = row<<16|seq and colDist = col|f16(dist)<<16 coalesced (nt).
// ---------------------------------------------------------------------------
__global__ __launch_bounds__(256) void count_kernel(
    const void* __restrict__ eidx, const float* __restrict__ coord,
    u32* __restrict__ counts, u32* __restrict__ rowseq,
    u32* __restrict__ colDist, int E)
{
    const bool is64 = detect_is64((const int*)eidx, E);
    const long long* e64 = (const long long*)eidx;
    const int*       e32 = (const int*)eidx;
    const int tid    = blockIdx.x * blockDim.x + threadIdx.x;
    const int stride = gridDim.x * blockDim.x;
    const int e4     = E & ~3;

    for (int e0 = tid * 4; e0 < e4; e0 += stride * 4) {
        int rows[4], cols[4];
        if (is64) {
            #pragma unroll
            for (int j = 0; j < 4; ++j) {
                rows[j] = (int)e64[e0 + j];
                cols[j] = (int)e64[E + e0 + j];
            }
        } else {
            #pragma unroll
            for (int j = 0; j < 4; ++j) {
                rows[j] = e32[e0 + j];
                cols[j] = e32[E + e0 + j];
            }
        }
        float dist[4];
        #pragma unroll
        for (int j = 0; j < 4; ++j) {
            float dx = coord[3 * rows[j] + 0] - coord[3 * cols[j] + 0];
            float dy = coord[3 * rows[j] + 1] - coord[3 * cols[j] + 1];
            float dz = coord[3 * rows[j] + 2] - coord[3 * cols[j] + 2];
            dist[j] = sqrtf(fmaf(dx, dx, fmaf(dy, dy, dz * dz)));
        }
        u32x4 rs, cd;
        #pragma unroll
        for (int j = 0; j < 4; ++j) {
            u32 seq = atomicAdd(&counts[rows[j]], 1u);
            rs[j] = ((u32)rows[j] << 16) | (seq & 0xFFFFu);
            cd[j] = (u32)cols[j] |
                    ((u32)__half_as_ushort(__float2half(dist[j])) << 16);
        }
        __builtin_nontemporal_store(rs, (u32x4*)&rowseq[e0]);
        __builtin_nontemporal_store(cd, (u32x4*)&colDist[e0]);
    }
    if (tid < E - e4) {        // scalar tail (E % 4 edges)
        int e = e4 + tid;
        int row = is64 ? (int)e64[e] : e32[e];
        int col = is64 ? (int)e64[E + e] : e32[E + e];
        float dx = coord[3 * row + 0] - coord[3 * col + 0];
        float dy = coord[3 * row + 1] - coord[3 * col + 1];
        float dz = coord[3 * row + 2] - coord[3 * col + 2];
        float dist = sqrtf(fmaf(dx, dx, fmaf(dy, dy, dz * dz)));
        u32 seq = atomicAdd(&counts[row], 1u);
        rowseq[e]  = ((u32)row << 16) | (seq & 0xFFFFu);
        colDist[e] = (u32)col | ((u32)__half_as_ushort(__float2half(dist)) << 16);
    }
}

// ---------------------------------------------------------------------------
// exclusive scan (N <= 65536)
// ---------------------------------------------------------------------------
__global__ __launch_bounds__(256) void scanA_kernel(
    const u32* __restrict__ counts, u32* __restrict__ chunkSum, int N)
{
    __shared__ u32 s[256];
    int t = threadIdx.x, i = blockIdx.x * 256 + t;
    s[t] = (i < N) ? counts[i] : 0u;
    __syncthreads();
    for (int off = 128; off > 0; off >>= 1) {
        if (t < off) s[t] += s[t + off];
        __syncthreads();
    }
    if (t == 0) chunkSum[blockIdx.x] = s[0];
}

__global__ __launch_bounds__(256) void scanB_kernel(
    const u32* __restrict__ chunkSum, u32* __restrict__ chunkBase,
    u32* __restrict__ offsets, int NCH, int N)
{
    __shared__ u32 s[256];
    int t = threadIdx.x;
    u32 v = (t < NCH) ? chunkSum[t] : 0u;
    s[t] = v;
    __syncthreads();
    for (int off = 1; off < 256; off <<= 1) {
        u32 a = (t >= off) ? s[t - off] : 0u;
        __syncthreads();
        s[t] += a;
        __syncthreads();
    }
    if (t < NCH) chunkBase[t] = s[t] - v;
    if (t == 255) offsets[N] = s[255];
}

__global__ __launch_bounds__(256) void scanC_kernel(
    const u32* __restrict__ counts, const u32* __restrict__ chunkBase,
    u32* __restrict__ offsets, int N)
{
    __shared__ u32 s[256];
    int t = threadIdx.x, i = blockIdx.x * 256 + t;
    u32 v = (i < N) ? counts[i] : 0u;
    s[t] = v;
    __syncthreads();
    for (int off = 1; off < 256; off <<= 1) {
        u32 a = (t >= off) ? s[t - off] : 0u;
        __syncthreads();
        s[t] += a;
        __syncthreads();
    }
    if (i < N) offsets[i] = s[t] - v + chunkBase[blockIdx.x];
}

// ---------------------------------------------------------------------------
// scatter: pos = offsets[row] + seq; packed[pos] = colDist. No atomics.
// ---------------------------------------------------------------------------
__global__ __launch_bounds__(256) void scatter_kernel(
    const u32* __restrict__ rowseq, const u32* __restrict__ colDist,
    const u32* __restrict__ offsets, u32* __restrict__ packed, int E)
{
    const int tid = blockIdx.x * blockDim.x + threadIdx.x;
    const int e4  = E & ~3;
    const int e0  = tid * 4;
    if (e0 < e4) {
        u32x4 rs = *(const u32x4*)&rowseq[e0];
        u32x4 cd = *(const u32x4*)&colDist[e0];
        u32 p0 = offsets[rs.x >> 16] + (rs.x & 0xFFFFu);
        u32 p1 = offsets[rs.y >> 16] + (rs.y & 0xFFFFu);
        u32 p2 = offsets[rs.z >> 16] + (rs.z & 0xFFFFu);
        u32 p3 = offsets[rs.w >> 16] + (rs.w & 0xFFFFu);
        __builtin_nontemporal_store(cd.x, &packed[p0]);
        __builtin_nontemporal_store(cd.y, &packed[p1]);
        __builtin_nontemporal_store(cd.z, &packed[p2]);
        __builtin_nontemporal_store(cd.w, &packed[p3]);
    }
    if (tid < E - e4) {
        int e = e4 + tid;
        u32 rs = rowseq[e];
        packed[offsets[rs >> 16] + (rs & 0xFFFFu)] = colDist[e];
    }
}

// ---------------------------------------------------------------------------
// pull aggregation -> H bf16. One wave/row, lane owns channels 2l,2l+1.
// 16-deep masked batch: for mean degree ~13, a row pays ONE serial gather
// round instead of two. Clamped loads + cndmask handle the tail.
// ---------------------------------------------------------------------------
__global__ __launch_bounds__(256) void aggregate_kernel(
    const u16* __restrict__ ybf, const u32* __restrict__ offsets,
    const u32* __restrict__ packed, const float* __restrict__ wc,
    u32* __restrict__ Hb2, int N)
{
    const int lane = threadIdx.x & 63;
    const int row  = blockIdx.x * 4 + (threadIdx.x >> 6);
    if (row >= N) return;

    const float2 wv = ((const float2*)wc)[lane];
    const float2 cv = ((const float2*)(wc + D))[lane];

    const u32 beg = offsets[row], end = offsets[row + 1];
    float a0[4] = {0.f, 0.f, 0.f, 0.f};
    float a1[4] = {0.f, 0.f, 0.f, 0.f};

    for (u32 base = beg; base < end; base += 16) {
        u32 p[16], yv[16];
        #pragma unroll
        for (int j = 0; j < 16; ++j) {
            u32 ee = base + j;
            p[j] = packed[ee < end ? ee : end - 1];
        }
        #pragma unroll
        for (int j = 0; j < 16; ++j)
            yv[j] = *(const u32*)(ybf + (size_t)(p[j] & 0xFFFFu) * D + 2 * lane);
        #pragma unroll
        for (int j = 0; j < 16; ++j) {
            float dt = __half2float(__ushort_as_half((u16)(p[j] >> 16)));
            float v0 = fmaxf(0.f, fmaf(dt, wv.x, __uint_as_float(yv[j] << 16)         + cv.x));
            float v1 = fmaxf(0.f, fmaf(dt, wv.y, __uint_as_float(yv[j] & 0xFFFF0000u) + cv.y));
            bool ok = (base + j) < end;
            a0[j & 3] += ok ? v0 : 0.f;
            a1[j & 3] += ok ? v1 : 0.f;
        }
    }
    float r0 = (a0[0] + a0[1]) + (a0[2] + a0[3]);
    float r1 = (a1[0] + a1[1]) + (a1[2] + a1[3]);
    Hb2[(size_t)row * 64 + lane] = (u32)f2bf(r0) | ((u32)f2bf(r1) << 16);
}

// ---------------------------------------------------------------------------
// MFMA GEMM: out[n][d] = A[n][:] @ W[:,d], K=D=128, via 16x16x32 bf16.
// AMODE 0: A f32 (convert while staging). AMODE 1: A already bf16.
// EPI 0: store bf16 (y). EPI 1: store f32 acc + x + deg*b2 (final out).
// ---------------------------------------------------------------------------
template <int AMODE, int EPI>
__global__ __launch_bounds__(256) void mfma_gemm_kernel(
    const void* __restrict__ Asrc, const u16* __restrict__ Wt,
    const float* __restrict__ xres, const u32* __restrict__ degi,
    const float* __restrict__ bvec, void* __restrict__ out, int N)
{
    __shared__ u16 wl[D * LDAP];
    __shared__ u16 al[64 * LDAP];
    const int t    = threadIdx.x;
    const int lane = t & 63;
    const int w    = t >> 6;
    const int n0   = blockIdx.x * 64;

    #pragma unroll
    for (int i = 0; i < 8; ++i) {
        int e = (i * 256 + t) * 8;
        int r = e >> 7, c = e & 127;
        *(u32x4*)&wl[r * LDAP + c] = *(const u32x4*)&Wt[r * D + c];
    }
    if (AMODE == 0) {
        const float* A = (const float*)Asrc;
        #pragma unroll
        for (int i = 0; i < 8; ++i) {
            int idx = i * 256 + t;
            int r = idx >> 5, c4 = idx & 31;
            int gr = n0 + r; if (gr >= N) gr = N - 1;
            float4 v = *(const float4*)&A[(size_t)gr * D + c4 * 4];
            u32 lo = (u32)f2bf(v.x) | ((u32)f2bf(v.y) << 16);
            u32 hi = (u32)f2bf(v.z) | ((u32)f2bf(v.w) << 16);
            *(uint2*)&al[r * LDAP + c4 * 4] = make_uint2(lo, hi);
        }
    } else {
        const u16* A = (const u16*)Asrc;
        #pragma unroll
        for (int i = 0; i < 4; ++i) {
            int idx = i * 256 + t;
            int r = idx >> 4, c8 = idx & 15;
            int gr = n0 + r; if (gr >= N) gr = N - 1;
            *(u32x4*)&al[r * LDAP + c8 * 8] = *(const u32x4*)&A[(size_t)gr * D + c8 * 8];
        }
    }
    __syncthreads();

    const int  fr     = lane & 15;
    const int  kg     = lane >> 4;
    const bool wvalid = (n0 + w * 16) < N;

    f32x4 acc[8];
    #pragma unroll
    for (int i = 0; i < 8; ++i) acc[i] = (f32x4){0.f, 0.f, 0.f, 0.f};

    #pragma unroll
    for (int kk = 0; kk < 4; ++kk) {
        const int ko = kk * 32 + kg * 8;
        s16x8 a = *(const s16x8*)&al[(w * 16 + fr) * LDAP + ko];
        #pragma unroll
        for (int ct = 0; ct < 8; ++ct) {
            s16x8 b = *(const s16x8*)&wl[(ct * 16 + fr) * LDAP + ko];
            acc[ct] = __builtin_amdgcn_mfma_f32_16x16x32_bf16(a, b, acc[ct], 0, 0, 0);
        }
    }

    if (!wvalid) return;

    if (EPI == 0) {
        u16* O = (u16*)out;
        #pragma unroll
        for (int ct = 0; ct < 8; ++ct) {
            const int c = ct * 16 + fr;
            #pragma unroll
            for (int j = 0; j < 4; ++j) {
                int R = n0 + w * 16 + 4 * kg + j;
                O[(size_t)R * D + c] = f2bf(acc[ct][j]);
            }
        }
    } else {
        float* O = (float*)out;
        float degf[4];
        #pragma unroll
        for (int j = 0; j < 4; ++j)
            degf[j] = (float)degi[n0 + w * 16 + 4 * kg + j];
        #pragma unroll
        for (int ct = 0; ct < 8; ++ct) {
            const int c  = ct * 16 + fr;
            const float bv = bvec[c];
            #pragma unroll
            for (int j = 0; j < 4; ++j) {
                int R = n0 + w * 16 + 4 * kg + j;
                float r = acc[ct][j] + xres[(size_t)R * D + c] + degf[j] * bv;
                O[(size_t)R * D + c] = r;
            }
        }
    }
}

// ---------------------------------------------------------------------------
extern "C" void kernel_launch(void* const* d_in, const int* in_sizes, int n_in,
                              void* d_out, int out_size, void* d_ws, size_t ws_size,
                              hipStream_t stream)
{
    const float* x      = (const float*)d_in[0];
    const float* coord  = (const float*)d_in[1];
    const void*  eidx   = d_in[2];
    const float* W_edge = (const float*)d_in[3];
    const float* b_edge = (const float*)d_in[4];
    const float* W1     = (const float*)d_in[5];
    const float* b1     = (const float*)d_in[6];
    const float* W2     = (const float*)d_in[7];
    const float* b2     = (const float*)d_in[8];

    const int N   = in_sizes[1] / 3;
    const int E   = in_sizes[2] / 2;
    const int EA  = (E + 3) & ~3;          // 16B-aligned element stride
    const int NCH = (N + 255) / 256;

    // ---- d_ws: Hb [N*D bf16] | counts [(N+16) u32] | wc [2D f32] | Wt1 | Wt2
    char* wsb    = (char*)d_ws;
    u16*  Hb     = (u16*)wsb;                 size_t o = (size_t)N * D * 2;
    u32*  counts = (u32*)(wsb + o);           o += (size_t)(N + 16) * 4;
    float* wc    = (float*)(wsb + o);         o += 2 * D * 4 + 64;
    u16*  Wt1    = (u16*)(wsb + o);           o += D * D * 2;
    u16*  Wt2    = (u16*)(wsb + o);

    // ---- d_out scratch (upper half; all dead before final GEMM writes):
    //   ybf [N*D bf16] | rowseq [EA] | colDist [EA] | packed [EA]
    //   | offsets [N+1] | chunkSum [NCH] | chunkBase [NCH]
    char* ob        = (char*)d_out;
    u16*  ybf       = (u16*)ob;
    u32*  rowseq    = (u32*)(ob + (size_t)N * D * 2);
    u32*  colDist   = rowseq + EA;
    u32*  packed    = colDist + EA;
    u32*  offsets   = packed + EA;
    u32*  chunkSum  = offsets + (N + 1);
    u32*  chunkBase = chunkSum + NCH;

    const int nz4 = (N + 16 + 3) / 4;
    const int ZB  = (nz4 + 127) / 128;
    prep_zero_kernel<<<D + 1 + ZB, 128, 0, stream>>>(
        W_edge, b_edge, W1, b1, W2, wc, Wt1, Wt2, (u32x4*)counts, nz4);

    const int CB = (E / 4 + 255) / 256;
    count_kernel<<<CB, 256, 0, stream>>>(eidx, coord, counts,
                                         rowseq, colDist, E);
    scanA_kernel<<<NCH, 256, 0, stream>>>(counts, chunkSum, N);
    scanB_kernel<<<1, 256, 0, stream>>>(chunkSum, chunkBase, offsets, NCH, N);
    scanC_kernel<<<NCH, 256, 0, stream>>>(counts, chunkBase, offsets, N);
    scatter_kernel<<<CB, 256, 0, stream>>>(rowseq, colDist, offsets, packed, E);

    const int GB = (N + 63) / 64;
    mfma_gemm_kernel<0, 0><<<GB, 256, 0, stream>>>(
        x, Wt1, nullptr, nullptr, nullptr, (void*)ybf, N);

    aggregate_kernel<<<(N + 3) / 4, 256, 0, stream>>>(
        ybf, offsets, packed, wc, (u32*)Hb, N);

    mfma_gemm_kernel<1, 1><<<GB, 256, 0, stream>>>(
        Hb, Wt2, x, counts, b2, d_out, N);
}

// Round 9
// 101.171 us; speedup vs baseline: 1.3195x; 1.2688x over previous
//
#include <hip/hip_runtime.h>
#include <hip/hip_fp16.h>
#include <hip/hip_bf16.h>
#include <math.h>

#define D 128
#define LDAP 136      // padded LDS row length (bf16 elems)
#define CAP 64        // bucket capacity per row (P(deg>64)~1e-40 at mean 12.8)
#define OVMAX 1024    // overflow list capacity (safety net, empty in practice)

typedef unsigned int   u32;
typedef unsigned short u16;
using f32x4 = __attribute__((ext_vector_type(4))) float;
using s16x8 = __attribute__((ext_vector_type(8))) short;
using u32x4 = __attribute__((ext_vector_type(4))) unsigned int;

__device__ __forceinline__ u16 f2bf(float f) {       // RNE f32->bf16
    u32 u = __float_as_uint(f);
    return (u16)((u + 0x7FFFu + ((u >> 16) & 1u)) >> 16);
}

// ---------------------------------------------------------------------------
// Per-wave int64-vs-int32 edge_index detection (high words of first 64
// elements all zero => int64). Deterministic, same answer in every block.
// ---------------------------------------------------------------------------
__device__ __forceinline__ bool detect_is64(const int* __restrict__ idx32, int E) {
    int lane = threadIdx.x & 63;
    int hi = 0;
    if (lane < E) hi = idx32[2 * lane + 1];
    return __ballot(hi != 0) == 0ull;
}

// ---------------------------------------------------------------------------
// prep+zero: blocks 0..127 transpose W1_top/W2 to bf16; block 128 builds
// w_vec/c_vec + zeroes ovCount; blocks 129.. zero counts (u32x4 granularity).
// ---------------------------------------------------------------------------
__global__ __launch_bounds__(128) void prep_zero_kernel(
    const float* __restrict__ W_edge, const float* __restrict__ b_edge,
    const float* __restrict__ W1, const float* __restrict__ b1,
    const float* __restrict__ W2, float* __restrict__ wc,
    u16* __restrict__ Wt1, u16* __restrict__ Wt2,
    u32x4* __restrict__ counts4, int nz4, u32* __restrict__ ovCount)
{
    const int b = blockIdx.x, t = threadIdx.x;
    if (b < D) {
        Wt1[b * D + t] = f2bf(W1[(size_t)t * D + b]);
        Wt2[b * D + t] = f2bf(W2[(size_t)t * D + b]);
    } else if (b == D) {
        if (t == 0) *ovCount = 0u;
        float w = 0.f, c = 0.f;
        #pragma unroll 8
        for (int k = 0; k < D; ++k) {
            float w1 = W1[(size_t)(D + k) * D + t];
            w = fmaf(W_edge[k], w1, w);
            c = fmaf(b_edge[k], w1, c);
        }
        wc[t]     = w;
        wc[D + t] = c + b1[t];
    } else {
        int i = (b - D - 1) * 128 + t;
        if (i < nz4) counts4[i] = (u32x4){0u, 0u, 0u, 0u};
    }
}

// ---------------------------------------------------------------------------
// count_direct: 4 edges/thread. seq = atomicAdd(counts[row]); store
// col|f16(dist)<<16 straight into the row's bucket. No scan, no scatter.
// Overflow (seq >= CAP) appends to a tiny list handled by aggregate.
// ---------------------------------------------------------------------------
__global__ __launch_bounds__(256) void count_direct_kernel(
    const void* __restrict__ eidx, const float* __restrict__ coord,
    u32* __restrict__ counts, u32* __restrict__ packed,
    u32* __restrict__ ovCount, u32* __restrict__ ovRow,
    u32* __restrict__ ovRec, int E)
{
    const bool is64 = detect_is64((const int*)eidx, E);
    const long long* e64 = (const long long*)eidx;
    const int*       e32 = (const int*)eidx;
    const int tid = blockIdx.x * blockDim.x + threadIdx.x;
    const int e4  = E & ~3;
    const int e0  = tid * 4;

    if (e0 < e4) {
        int rows[4], cols[4];
        if (is64) {
            #pragma unroll
            for (int j = 0; j < 4; ++j) {
                rows[j] = (int)e64[e0 + j];
                cols[j] = (int)e64[E + e0 + j];
            }
        } else {
            #pragma unroll
            for (int j = 0; j < 4; ++j) {
                rows[j] = e32[e0 + j];
                cols[j] = e32[E + e0 + j];
            }
        }
        u32 rec[4];
        #pragma unroll
        for (int j = 0; j < 4; ++j) {
            float dx = coord[3 * rows[j] + 0] - coord[3 * cols[j] + 0];
            float dy = coord[3 * rows[j] + 1] - coord[3 * cols[j] + 1];
            float dz = coord[3 * rows[j] + 2] - coord[3 * cols[j] + 2];
            float dist = sqrtf(fmaf(dx, dx, fmaf(dy, dy, dz * dz)));
            rec[j] = (u32)cols[j] |
                     ((u32)__half_as_ushort(__float2half(dist)) << 16);
        }
        u32 seq[4];
        #pragma unroll
        for (int j = 0; j < 4; ++j)
            seq[j] = atomicAdd(&counts[rows[j]], 1u);
        #pragma unroll
        for (int j = 0; j < 4; ++j) {
            if (seq[j] < (u32)CAP) {
                __builtin_nontemporal_store(
                    rec[j], &packed[((u32)rows[j] << 6) + seq[j]]);
            } else {
                u32 k = atomicAdd(ovCount, 1u);
                if (k < (u32)OVMAX) { ovRow[k] = (u32)rows[j]; ovRec[k] = rec[j]; }
            }
        }
    }
    if (tid < E - e4) {        // scalar tail (E % 4 edges)
        int e = e4 + tid;
        int row = is64 ? (int)e64[e] : e32[e];
        int col = is64 ? (int)e64[E + e] : e32[E + e];
        float dx = coord[3 * row + 0] - coord[3 * col + 0];
        float dy = coord[3 * row + 1] - coord[3 * col + 1];
        float dz = coord[3 * row + 2] - coord[3 * col + 2];
        float dist = sqrtf(fmaf(dx, dx, fmaf(dy, dy, dz * dz)));
        u32 rec = (u32)col | ((u32)__half_as_ushort(__float2half(dist)) << 16);
        u32 seq = atomicAdd(&counts[row], 1u);
        if (seq < (u32)CAP) {
            packed[((u32)row << 6) + seq] = rec;
        } else {
            u32 k = atomicAdd(ovCount, 1u);
            if (k < (u32)OVMAX) { ovRow[k] = (u32)row; ovRec[k] = rec; }
        }
    }
}

// ---------------------------------------------------------------------------
// pull aggregation -> H bf16. One wave/row, lane owns channels 2l,2l+1.
// Bucket layout: row's records at [row*CAP, row*CAP+min(deg,CAP)).
// 16-deep masked batch (mean degree ~13 -> one serial gather round).
// Overflow rows (deg > CAP) sweep the tiny overflow list (empty in practice).
// ---------------------------------------------------------------------------
__global__ __launch_bounds__(256) void aggregate_kernel(
    const u16* __restrict__ ybf, const u32* __restrict__ counts,
    const u32* __restrict__ packed, const float* __restrict__ wc,
    u32* __restrict__ Hb2, const u32* __restrict__ ovCount,
    const u32* __restrict__ ovRow, const u32* __restrict__ ovRec, int N)
{
    const int lane = threadIdx.x & 63;
    const int row  = blockIdx.x * 4 + (threadIdx.x >> 6);
    if (row >= N) return;

    const float2 wv = ((const float2*)wc)[lane];
    const float2 cv = ((const float2*)(wc + D))[lane];

    const u32 deg = counts[row];
    const u32 beg = (u32)row << 6;
    const u32 end = beg + (deg < (u32)CAP ? deg : (u32)CAP);
    float a0[4] = {0.f, 0.f, 0.f, 0.f};
    float a1[4] = {0.f, 0.f, 0.f, 0.f};

    for (u32 base = beg; base < end; base += 16) {
        u32 p[16], yv[16];
        #pragma unroll
        for (int j = 0; j < 16; ++j) {
            u32 ee = base + j;
            p[j] = packed[ee < end ? ee : end - 1];
        }
        #pragma unroll
        for (int j = 0; j < 16; ++j)
            yv[j] = *(const u32*)(ybf + (size_t)(p[j] & 0xFFFFu) * D + 2 * lane);
        #pragma unroll
        for (int j = 0; j < 16; ++j) {
            float dt = __half2float(__ushort_as_half((u16)(p[j] >> 16)));
            float v0 = fmaxf(0.f, fmaf(dt, wv.x, __uint_as_float(yv[j] << 16)         + cv.x));
            float v1 = fmaxf(0.f, fmaf(dt, wv.y, __uint_as_float(yv[j] & 0xFFFF0000u) + cv.y));
            bool ok = (base + j) < end;
            a0[j & 3] += ok ? v0 : 0.f;
            a1[j & 3] += ok ? v1 : 0.f;
        }
    }
    if (deg > (u32)CAP) {                       // safety net, empty in practice
        u32 ov = *ovCount; if (ov > (u32)OVMAX) ov = (u32)OVMAX;
        for (u32 i = 0; i < ov; ++i) {
            if (ovRow[i] == (u32)row) {
                u32 pr = ovRec[i];
                float dt = __half2float(__ushort_as_half((u16)(pr >> 16)));
                u32 yv = *(const u32*)(ybf + (size_t)(pr & 0xFFFFu) * D + 2 * lane);
                a0[0] += fmaxf(0.f, fmaf(dt, wv.x, __uint_as_float(yv << 16)         + cv.x));
                a1[0] += fmaxf(0.f, fmaf(dt, wv.y, __uint_as_float(yv & 0xFFFF0000u) + cv.y));
            }
        }
    }
    float r0 = (a0[0] + a0[1]) + (a0[2] + a0[3]);
    float r1 = (a1[0] + a1[1]) + (a1[2] + a1[3]);
    Hb2[(size_t)row * 64 + lane] = (u32)f2bf(r0) | ((u32)f2bf(r1) << 16);
}

// ---------------------------------------------------------------------------
// MFMA GEMM: out[n][d] = A[n][:] @ W[:,d], K=D=128, via 16x16x32 bf16.
// AMODE 0: A f32 (convert while staging). AMODE 1: A already bf16.
// EPI 0: store bf16 (y). EPI 1: store f32 acc + x + deg*b2 (final out).
// ---------------------------------------------------------------------------
template <int AMODE, int EPI>
__global__ __launch_bounds__(256) void mfma_gemm_kernel(
    const void* __restrict__ Asrc, const u16* __restrict__ Wt,
    const float* __restrict__ xres, const u32* __restrict__ degi,
    const float* __restrict__ bvec, void* __restrict__ out, int N)
{
    __shared__ u16 wl[D * LDAP];
    __shared__ u16 al[64 * LDAP];
    const int t    = threadIdx.x;
    const int lane = t & 63;
    const int w    = t >> 6;
    const int n0   = blockIdx.x * 64;

    #pragma unroll
    for (int i = 0; i < 8; ++i) {
        int e = (i * 256 + t) * 8;
        int r = e >> 7, c = e & 127;
        *(u32x4*)&wl[r * LDAP + c] = *(const u32x4*)&Wt[r * D + c];
    }
    if (AMODE == 0) {
        const float* A = (const float*)Asrc;
        #pragma unroll
        for (int i = 0; i < 8; ++i) {
            int idx = i * 256 + t;
            int r = idx >> 5, c4 = idx & 31;
            int gr = n0 + r; if (gr >= N) gr = N - 1;
            float4 v = *(const float4*)&A[(size_t)gr * D + c4 * 4];
            u32 lo = (u32)f2bf(v.x) | ((u32)f2bf(v.y) << 16);
            u32 hi = (u32)f2bf(v.z) | ((u32)f2bf(v.w) << 16);
            *(uint2*)&al[r * LDAP + c4 * 4] = make_uint2(lo, hi);
        }
    } else {
        const u16* A = (const u16*)Asrc;
        #pragma unroll
        for (int i = 0; i < 4; ++i) {
            int idx = i * 256 + t;
            int r = idx >> 4, c8 = idx & 15;
            int gr = n0 + r; if (gr >= N) gr = N - 1;
            *(u32x4*)&al[r * LDAP + c8 * 8] = *(const u32x4*)&A[(size_t)gr * D + c8 * 8];
        }
    }
    __syncthreads();

    const int  fr     = lane & 15;
    const int  kg     = lane >> 4;
    const bool wvalid = (n0 + w * 16) < N;

    f32x4 acc[8];
    #pragma unroll
    for (int i = 0; i < 8; ++i) acc[i] = (f32x4){0.f, 0.f, 0.f, 0.f};

    #pragma unroll
    for (int kk = 0; kk < 4; ++kk) {
        const int ko = kk * 32 + kg * 8;
        s16x8 a = *(const s16x8*)&al[(w * 16 + fr) * LDAP + ko];
        #pragma unroll
        for (int ct = 0; ct < 8; ++ct) {
            s16x8 b = *(const s16x8*)&wl[(ct * 16 + fr) * LDAP + ko];
            acc[ct] = __builtin_amdgcn_mfma_f32_16x16x32_bf16(a, b, acc[ct], 0, 0, 0);
        }
    }

    if (!wvalid) return;

    if (EPI == 0) {
        u16* O = (u16*)out;
        #pragma unroll
        for (int ct = 0; ct < 8; ++ct) {
            const int c = ct * 16 + fr;
            #pragma unroll
            for (int j = 0; j < 4; ++j) {
                int R = n0 + w * 16 + 4 * kg + j;
                O[(size_t)R * D + c] = f2bf(acc[ct][j]);
            }
        }
    } else {
        float* O = (float*)out;
        float degf[4];
        #pragma unroll
        for (int j = 0; j < 4; ++j)
            degf[j] = (float)degi[n0 + w * 16 + 4 * kg + j];
        #pragma unroll
        for (int ct = 0; ct < 8; ++ct) {
            const int c  = ct * 16 + fr;
            const float bv = bvec[c];
            #pragma unroll
            for (int j = 0; j < 4; ++j) {
                int R = n0 + w * 16 + 4 * kg + j;
                float r = acc[ct][j] + xres[(size_t)R * D + c] + degf[j] * bv;
                O[(size_t)R * D + c] = r;
            }
        }
    }
}

// ---------------------------------------------------------------------------
extern "C" void kernel_launch(void* const* d_in, const int* in_sizes, int n_in,
                              void* d_out, int out_size, void* d_ws, size_t ws_size,
                              hipStream_t stream)
{
    const float* x      = (const float*)d_in[0];
    const float* coord  = (const float*)d_in[1];
    const void*  eidx   = d_in[2];
    const float* W_edge = (const float*)d_in[3];
    const float* b_edge = (const float*)d_in[4];
    const float* W1     = (const float*)d_in[5];
    const float* b1     = (const float*)d_in[6];
    const float* W2     = (const float*)d_in[7];
    const float* b2     = (const float*)d_in[8];

    const int N = in_sizes[1] / 3;
    const int E = in_sizes[2] / 2;

    // ---- d_ws: Hb [N*D bf16] | counts [(N+16) u32] | wc [2D f32]
    //            | Wt1 | Wt2 | ovCount | ovRow[OVMAX] | ovRec[OVMAX]
    char* wsb    = (char*)d_ws;
    u16*  Hb     = (u16*)wsb;                 size_t o = (size_t)N * D * 2;
    u32*  counts = (u32*)(wsb + o);           o += (size_t)(N + 16) * 4;
    float* wc    = (float*)(wsb + o);         o += 2 * D * 4 + 64;
    u16*  Wt1    = (u16*)(wsb + o);           o += D * D * 2;
    u16*  Wt2    = (u16*)(wsb + o);           o += D * D * 2;
    u32*  ovCount = (u32*)(wsb + o);          o += 64;
    u32*  ovRow   = (u32*)(wsb + o);          o += OVMAX * 4;
    u32*  ovRec   = (u32*)(wsb + o);

    // ---- d_out scratch: ybf [N*D bf16] | packed [N*CAP u32] (exactly fills
    //      N*D*4 bytes; both dead before the final GEMM overwrites d_out)
    char* ob     = (char*)d_out;
    u16*  ybf    = (u16*)ob;
    u32*  packed = (u32*)(ob + (size_t)N * D * 2);

    const int nz4 = (N + 16 + 3) / 4;
    const int ZB  = (nz4 + 127) / 128;
    prep_zero_kernel<<<D + 1 + ZB, 128, 0, stream>>>(
        W_edge, b_edge, W1, b1, W2, wc, Wt1, Wt2, (u32x4*)counts, nz4, ovCount);

    const int CB = (E / 4 + 255) / 256;
    count_direct_kernel<<<CB, 256, 0, stream>>>(
        eidx, coord, counts, packed, ovCount, ovRow, ovRec, E);

    const int GB = (N + 63) / 64;
    mfma_gemm_kernel<0, 0><<<GB, 256, 0, stream>>>(
        x, Wt1, nullptr, nullptr, nullptr, (void*)ybf, N);

    aggregate_kernel<<<(N + 3) / 4, 256, 0, stream>>>(
        ybf, counts, packed, wc, (u32*)Hb, ovCount, ovRow, ovRec, N);

    mfma_gemm_kernel<1, 1><<<GB, 256, 0, stream>>>(
        Hb, Wt2, x, counts, b2, d_out, N);
}

// Round 10
// 99.823 us; speedup vs baseline: 1.3374x; 1.0135x over previous
//
#include <hip/hip_runtime.h>
#include <hip/hip_fp16.h>
#include <hip/hip_bf16.h>
#include <math.h>

#define D 128
#define LDAP 136      // padded LDS row length (bf16 elems)
#define CAP 64        // bucket capacity per row (P(deg>64)~1e-40 at mean 12.8)
#define OVMAX 1024    // overflow list capacity (safety net, empty in practice)

typedef unsigned int   u32;
typedef unsigned short u16;
using f32x4 = __attribute__((ext_vector_type(4))) float;
using s16x8 = __attribute__((ext_vector_type(8))) short;
using u32x4 = __attribute__((ext_vector_type(4))) unsigned int;

__device__ __forceinline__ u16 f2bf(float f) {       // RNE f32->bf16
    u32 u = __float_as_uint(f);
    return (u16)((u + 0x7FFFu + ((u >> 16) & 1u)) >> 16);
}

// ---------------------------------------------------------------------------
// Per-wave int64-vs-int32 edge_index detection (high words of first 64
// elements all zero => int64). Deterministic, same answer in every block.
// ---------------------------------------------------------------------------
__device__ __forceinline__ bool detect_is64(const int* __restrict__ idx32, int E) {
    int lane = threadIdx.x & 63;
    int hi = 0;
    if (lane < E) hi = idx32[2 * lane + 1];
    return __ballot(hi != 0) == 0ull;
}

// ---------------------------------------------------------------------------
// prep+zero: blocks 0..127 transpose W1_top/W2 to bf16; block 128 builds
// w_vec/c_vec + zeroes ovCount; blocks 129.. zero counts (u32x4 granularity).
// ---------------------------------------------------------------------------
__global__ __launch_bounds__(128) void prep_zero_kernel(
    const float* __restrict__ W_edge, const float* __restrict__ b_edge,
    const float* __restrict__ W1, const float* __restrict__ b1,
    const float* __restrict__ W2, float* __restrict__ wc,
    u16* __restrict__ Wt1, u16* __restrict__ Wt2,
    u32x4* __restrict__ counts4, int nz4, u32* __restrict__ ovCount)
{
    const int b = blockIdx.x, t = threadIdx.x;
    if (b < D) {
        Wt1[b * D + t] = f2bf(W1[(size_t)t * D + b]);
        Wt2[b * D + t] = f2bf(W2[(size_t)t * D + b]);
    } else if (b == D) {
        if (t == 0) *ovCount = 0u;
        float w = 0.f, c = 0.f;
        #pragma unroll 8
        for (int k = 0; k < D; ++k) {
            float w1 = W1[(size_t)(D + k) * D + t];
            w = fmaf(W_edge[k], w1, w);
            c = fmaf(b_edge[k], w1, c);
        }
        wc[t]     = w;
        wc[D + t] = c + b1[t];
    } else {
        int i = (b - D - 1) * 128 + t;
        if (i < nz4) counts4[i] = (u32x4){0u, 0u, 0u, 0u};
    }
}

// ---------------------------------------------------------------------------
// count_direct: ONE edge per thread (max TLP: E/64 waves saturate all wave
// slots; latency of coord gather / atomic / scattered store hides across
// waves instead of serializing inside a thread).
// seq = atomicAdd(counts[row]); packed[row*64+seq] = col|f16(dist)<<16.
// ---------------------------------------------------------------------------
__global__ __launch_bounds__(256) void count_direct_kernel(
    const void* __restrict__ eidx, const float* __restrict__ coord,
    u32* __restrict__ counts, u32* __restrict__ packed,
    u32* __restrict__ ovCount, u32* __restrict__ ovRow,
    u32* __restrict__ ovRec, int E)
{
    const bool is64 = detect_is64((const int*)eidx, E);
    const long long* e64 = (const long long*)eidx;
    const int*       e32 = (const int*)eidx;
    const int e = blockIdx.x * 256 + threadIdx.x;
    if (e >= E) return;

    int row, col;
    if (is64) { row = (int)e64[e]; col = (int)e64[E + e]; }
    else      { row = e32[e];      col = e32[E + e];      }

    // atomic is independent of the coord gather -> both in flight at once
    u32 seq = atomicAdd(&counts[row], 1u);

    float dx = coord[3 * row + 0] - coord[3 * col + 0];
    float dy = coord[3 * row + 1] - coord[3 * col + 1];
    float dz = coord[3 * row + 2] - coord[3 * col + 2];
    float dist = sqrtf(fmaf(dx, dx, fmaf(dy, dy, dz * dz)));
    u32 rec = (u32)col | ((u32)__half_as_ushort(__float2half(dist)) << 16);

    if (seq < (u32)CAP) {
        __builtin_nontemporal_store(rec, &packed[((u32)row << 6) + seq]);
    } else {
        u32 k = atomicAdd(ovCount, 1u);
        if (k < (u32)OVMAX) { ovRow[k] = (u32)row; ovRec[k] = rec; }
    }
}

// ---------------------------------------------------------------------------
// pull aggregation -> H bf16. One wave/row, lane owns channels 2l,2l+1.
// Bucket layout: row's records at [row*CAP, row*CAP+min(deg,CAP)).
// 16-deep masked batch (mean degree ~13 -> one serial gather round).
// Overflow rows (deg > CAP) sweep the tiny overflow list (empty in practice).
// ---------------------------------------------------------------------------
__global__ __launch_bounds__(256) void aggregate_kernel(
    const u16* __restrict__ ybf, const u32* __restrict__ counts,
    const u32* __restrict__ packed, const float* __restrict__ wc,
    u32* __restrict__ Hb2, const u32* __restrict__ ovCount,
    const u32* __restrict__ ovRow, const u32* __restrict__ ovRec, int N)
{
    const int lane = threadIdx.x & 63;
    const int row  = blockIdx.x * 4 + (threadIdx.x >> 6);
    if (row >= N) return;

    const float2 wv = ((const float2*)wc)[lane];
    const float2 cv = ((const float2*)(wc + D))[lane];

    const u32 deg = counts[row];
    const u32 beg = (u32)row << 6;
    const u32 end = beg + (deg < (u32)CAP ? deg : (u32)CAP);
    float a0[4] = {0.f, 0.f, 0.f, 0.f};
    float a1[4] = {0.f, 0.f, 0.f, 0.f};

    for (u32 base = beg; base < end; base += 16) {
        u32 p[16], yv[16];
        #pragma unroll
        for (int j = 0; j < 16; ++j) {
            u32 ee = base + j;
            p[j] = packed[ee < end ? ee : end - 1];
        }
        #pragma unroll
        for (int j = 0; j < 16; ++j)
            yv[j] = *(const u32*)(ybf + (size_t)(p[j] & 0xFFFFu) * D + 2 * lane);
        #pragma unroll
        for (int j = 0; j < 16; ++j) {
            float dt = __half2float(__ushort_as_half((u16)(p[j] >> 16)));
            float v0 = fmaxf(0.f, fmaf(dt, wv.x, __uint_as_float(yv[j] << 16)         + cv.x));
            float v1 = fmaxf(0.f, fmaf(dt, wv.y, __uint_as_float(yv[j] & 0xFFFF0000u) + cv.y));
            bool ok = (base + j) < end;
            a0[j & 3] += ok ? v0 : 0.f;
            a1[j & 3] += ok ? v1 : 0.f;
        }
    }
    if (deg > (u32)CAP) {                       // safety net, empty in practice
        u32 ov = *ovCount; if (ov > (u32)OVMAX) ov = (u32)OVMAX;
        for (u32 i = 0; i < ov; ++i) {
            if (ovRow[i] == (u32)row) {
                u32 pr = ovRec[i];
                float dt = __half2float(__ushort_as_half((u16)(pr >> 16)));
                u32 yv = *(const u32*)(ybf + (size_t)(pr & 0xFFFFu) * D + 2 * lane);
                a0[0] += fmaxf(0.f, fmaf(dt, wv.x, __uint_as_float(yv << 16)         + cv.x));
                a1[0] += fmaxf(0.f, fmaf(dt, wv.y, __uint_as_float(yv & 0xFFFF0000u) + cv.y));
            }
        }
    }
    float r0 = (a0[0] + a0[1]) + (a0[2] + a0[3]);
    float r1 = (a1[0] + a1[1]) + (a1[2] + a1[3]);
    Hb2[(size_t)row * 64 + lane] = (u32)f2bf(r0) | ((u32)f2bf(r1) << 16);
}

// ---------------------------------------------------------------------------
// MFMA GEMM: out[n][d] = A[n][:] @ W[:,d], K=D=128, via 16x16x32 bf16.
// AMODE 0: A f32 (convert while staging). AMODE 1: A already bf16.
// EPI 0: store bf16 (y). EPI 1: store f32 acc + x + deg*b2 (final out).
// ---------------------------------------------------------------------------
template <int AMODE, int EPI>
__global__ __launch_bounds__(256) void mfma_gemm_kernel(
    const void* __restrict__ Asrc, const u16* __restrict__ Wt,
    const float* __restrict__ xres, const u32* __restrict__ degi,
    const float* __restrict__ bvec, void* __restrict__ out, int N)
{
    __shared__ u16 wl[D * LDAP];
    __shared__ u16 al[64 * LDAP];
    const int t    = threadIdx.x;
    const int lane = t & 63;
    const int w    = t >> 6;
    const int n0   = blockIdx.x * 64;

    #pragma unroll
    for (int i = 0; i < 8; ++i) {
        int e = (i * 256 + t) * 8;
        int r = e >> 7, c = e & 127;
        *(u32x4*)&wl[r * LDAP + c] = *(const u32x4*)&Wt[r * D + c];
    }
    if (AMODE == 0) {
        const float* A = (const float*)Asrc;
        #pragma unroll
        for (int i = 0; i < 8; ++i) {
            int idx = i * 256 + t;
            int r = idx >> 5, c4 = idx & 31;
            int gr = n0 + r; if (gr >= N) gr = N - 1;
            float4 v = *(const float4*)&A[(size_t)gr * D + c4 * 4];
            u32 lo = (u32)f2bf(v.x) | ((u32)f2bf(v.y) << 16);
            u32 hi = (u32)f2bf(v.z) | ((u32)f2bf(v.w) << 16);
            *(uint2*)&al[r * LDAP + c4 * 4] = make_uint2(lo, hi);
        }
    } else {
        const u16* A = (const u16*)Asrc;
        #pragma unroll
        for (int i = 0; i < 4; ++i) {
            int idx = i * 256 + t;
            int r = idx >> 4, c8 = idx & 15;
            int gr = n0 + r; if (gr >= N) gr = N - 1;
            *(u32x4*)&al[r * LDAP + c8 * 8] = *(const u32x4*)&A[(size_t)gr * D + c8 * 8];
        }
    }
    __syncthreads();

    const int  fr     = lane & 15;
    const int  kg     = lane >> 4;
    const bool wvalid = (n0 + w * 16) < N;

    f32x4 acc[8];
    #pragma unroll
    for (int i = 0; i < 8; ++i) acc[i] = (f32x4){0.f, 0.f, 0.f, 0.f};

    #pragma unroll
    for (int kk = 0; kk < 4; ++kk) {
        const int ko = kk * 32 + kg * 8;
        s16x8 a = *(const s16x8*)&al[(w * 16 + fr) * LDAP + ko];
        #pragma unroll
        for (int ct = 0; ct < 8; ++ct) {
            s16x8 b = *(const s16x8*)&wl[(ct * 16 + fr) * LDAP + ko];
            acc[ct] = __builtin_amdgcn_mfma_f32_16x16x32_bf16(a, b, acc[ct], 0, 0, 0);
        }
    }

    if (!wvalid) return;

    if (EPI == 0) {
        u16* O = (u16*)out;
        #pragma unroll
        for (int ct = 0; ct < 8; ++ct) {
            const int c = ct * 16 + fr;
            #pragma unroll
            for (int j = 0; j < 4; ++j) {
                int R = n0 + w * 16 + 4 * kg + j;
                O[(size_t)R * D + c] = f2bf(acc[ct][j]);
            }
        }
    } else {
        float* O = (float*)out;
        float degf[4];
        #pragma unroll
        for (int j = 0; j < 4; ++j)
            degf[j] = (float)degi[n0 + w * 16 + 4 * kg + j];
        #pragma unroll
        for (int ct = 0; ct < 8; ++ct) {
            const int c  = ct * 16 + fr;
            const float bv = bvec[c];
            #pragma unroll
            for (int j = 0; j < 4; ++j) {
                int R = n0 + w * 16 + 4 * kg + j;
                float r = acc[ct][j] + xres[(size_t)R * D + c] + degf[j] * bv;
                O[(size_t)R * D + c] = r;
            }
        }
    }
}

// ---------------------------------------------------------------------------
extern "C" void kernel_launch(void* const* d_in, const int* in_sizes, int n_in,
                              void* d_out, int out_size, void* d_ws, size_t ws_size,
                              hipStream_t stream)
{
    const float* x      = (const float*)d_in[0];
    const float* coord  = (const float*)d_in[1];
    const void*  eidx   = d_in[2];
    const float* W_edge = (const float*)d_in[3];
    const float* b_edge = (const float*)d_in[4];
    const float* W1     = (const float*)d_in[5];
    const float* b1     = (const float*)d_in[6];
    const float* W2     = (const float*)d_in[7];
    const float* b2     = (const float*)d_in[8];

    const int N = in_sizes[1] / 3;
    const int E = in_sizes[2] / 2;

    // ---- d_ws: Hb [N*D bf16] | counts [(N+16) u32] | wc [2D f32]
    //            | Wt1 | Wt2 | ovCount | ovRow[OVMAX] | ovRec[OVMAX]
    char* wsb    = (char*)d_ws;
    u16*  Hb     = (u16*)wsb;                 size_t o = (size_t)N * D * 2;
    u32*  counts = (u32*)(wsb + o);           o += (size_t)(N + 16) * 4;
    float* wc    = (float*)(wsb + o);         o += 2 * D * 4 + 64;
    u16*  Wt1    = (u16*)(wsb + o);           o += D * D * 2;
    u16*  Wt2    = (u16*)(wsb + o);           o += D * D * 2;
    u32*  ovCount = (u32*)(wsb + o);          o += 64;
    u32*  ovRow   = (u32*)(wsb + o);          o += OVMAX * 4;
    u32*  ovRec   = (u32*)(wsb + o);

    // ---- d_out scratch: ybf [N*D bf16] | packed [N*CAP u32] (exactly fills
    //      N*D*4 bytes; both dead before the final GEMM overwrites d_out)
    char* ob     = (char*)d_out;
    u16*  ybf    = (u16*)ob;
    u32*  packed = (u32*)(ob + (size_t)N * D * 2);

    const int nz4 = (N + 16 + 3) / 4;
    const int ZB  = (nz4 + 127) / 128;
    prep_zero_kernel<<<D + 1 + ZB, 128, 0, stream>>>(
        W_edge, b_edge, W1, b1, W2, wc, Wt1, Wt2, (u32x4*)counts, nz4, ovCount);

    const int CB = (E + 255) / 256;            // ONE edge per thread
    count_direct_kernel<<<CB, 256, 0, stream>>>(
        eidx, coord, counts, packed, ovCount, ovRow, ovRec, E);

    const int GB = (N + 63) / 64;
    mfma_gemm_kernel<0, 0><<<GB, 256, 0, stream>>>(
        x, Wt1, nullptr, nullptr, nullptr, (void*)ybf, N);

    aggregate_kernel<<<(N + 3) / 4, 256, 0, stream>>>(
        ybf, counts, packed, wc, (u32*)Hb, ovCount, ovRow, ovRec, N);

    mfma_gemm_kernel<1, 1><<<GB, 256, 0, stream>>>(
        Hb, Wt2, x, counts, b2, d_out, N);
}

// Round 11
// 92.618 us; speedup vs baseline: 1.4414x; 1.0778x over previous
//
#include <hip/hip_runtime.h>
#include <hip/hip_fp16.h>
#include <hip/hip_bf16.h>
#include <math.h>

#define D 128
#define LDAP 136      // padded LDS row length (bf16 elems)
#define CAP 64        // bucket capacity per row (P(deg>64)~1e-40 at mean 12.8)
#define OVMAX 1024    // overflow list capacity (safety net, empty in practice)

typedef unsigned int   u32;
typedef unsigned short u16;
using f32x4 = __attribute__((ext_vector_type(4))) float;
using s16x8 = __attribute__((ext_vector_type(8))) short;
using u32x4 = __attribute__((ext_vector_type(4))) unsigned int;

__device__ __forceinline__ u16 f2bf(float f) {       // RNE f32->bf16
    u32 u = __float_as_uint(f);
    return (u16)((u + 0x7FFFu + ((u >> 16) & 1u)) >> 16);
}

// ---------------------------------------------------------------------------
// Per-wave int64-vs-int32 edge_index detection (high words of first 64
// elements all zero => int64). Deterministic, same answer in every block.
// ---------------------------------------------------------------------------
__device__ __forceinline__ bool detect_is64(const int* __restrict__ idx32, int E) {
    int lane = threadIdx.x & 63;
    int hi = 0;
    if (lane < E) hi = idx32[2 * lane + 1];
    return __ballot(hi != 0) == 0ull;
}

// ---------------------------------------------------------------------------
// prep+zero: blocks 0..127 transpose W1_top/W2 to bf16; block 128 builds
// w_vec/c_vec + zeroes ovCount; blocks 129.. zero counts (u32x4 granularity).
// ---------------------------------------------------------------------------
__global__ __launch_bounds__(128) void prep_zero_kernel(
    const float* __restrict__ W_edge, const float* __restrict__ b_edge,
    const float* __restrict__ W1, const float* __restrict__ b1,
    const float* __restrict__ W2, float* __restrict__ wc,
    u16* __restrict__ Wt1, u16* __restrict__ Wt2,
    u32x4* __restrict__ counts4, int nz4, u32* __restrict__ ovCount)
{
    const int b = blockIdx.x, t = threadIdx.x;
    if (b < D) {
        Wt1[b * D + t] = f2bf(W1[(size_t)t * D + b]);
        Wt2[b * D + t] = f2bf(W2[(size_t)t * D + b]);
    } else if (b == D) {
        if (t == 0) *ovCount = 0u;
        float w = 0.f, c = 0.f;
        #pragma unroll 8
        for (int k = 0; k < D; ++k) {
            float w1 = W1[(size_t)(D + k) * D + t];
            w = fmaf(W_edge[k], w1, w);
            c = fmaf(b_edge[k], w1, c);
        }
        wc[t]     = w;
        wc[D + t] = c + b1[t];
    } else {
        int i = (b - D - 1) * 128 + t;
        if (i < nz4) counts4[i] = (u32x4){0u, 0u, 0u, 0u};
    }
}

// ---------------------------------------------------------------------------
// FUSED count + gemm1 (independent work, one launch; count blocks first —
// they're the 44us critical path; gemm1's MFMA waves backfill the idle
// matrix pipe while count waves stall on atomics/scattered stores).
// Blocks [0,CB): count path — seq = atomicAdd(counts[row]);
//   packed[row*64+seq] = col|f16(dist)<<16 (plain store: batch in L2).
// Blocks [CB,CB+GB): gemm1 path — ybf = bf16(x @ W1_top) via MFMA.
// ---------------------------------------------------------------------------
__global__ __launch_bounds__(256) void count_gemm1_kernel(
    const void* __restrict__ eidx, const float* __restrict__ coord,
    u32* __restrict__ counts, u32* __restrict__ packed,
    u32* __restrict__ ovCount, u32* __restrict__ ovRow,
    u32* __restrict__ ovRec, int E, int CB,
    const float* __restrict__ A, const u16* __restrict__ Wt,
    u16* __restrict__ ybf, int N)
{
    __shared__ u16 wl[D * LDAP];
    __shared__ u16 al[64 * LDAP];

    if ((int)blockIdx.x < CB) {
        // ---------------- count path ----------------
        const bool is64 = detect_is64((const int*)eidx, E);
        const long long* e64 = (const long long*)eidx;
        const int*       e32 = (const int*)eidx;
        const int e = blockIdx.x * 256 + threadIdx.x;
        if (e >= E) return;

        int row, col;
        if (is64) { row = (int)e64[e]; col = (int)e64[E + e]; }
        else      { row = e32[e];      col = e32[E + e];      }

        u32 seq = atomicAdd(&counts[row], 1u);   // independent of coord gather

        float dx = coord[3 * row + 0] - coord[3 * col + 0];
        float dy = coord[3 * row + 1] - coord[3 * col + 1];
        float dz = coord[3 * row + 2] - coord[3 * col + 2];
        float dist = sqrtf(fmaf(dx, dx, fmaf(dy, dy, dz * dz)));
        u32 rec = (u32)col | ((u32)__half_as_ushort(__float2half(dist)) << 16);

        if (seq < (u32)CAP) {
            packed[((u32)row << 6) + seq] = rec;
        } else {
            u32 k = atomicAdd(ovCount, 1u);
            if (k < (u32)OVMAX) { ovRow[k] = (u32)row; ovRec[k] = rec; }
        }
        return;
    }

    // ---------------- gemm1 path ----------------
    const int bid  = blockIdx.x - CB;
    const int t    = threadIdx.x;
    const int lane = t & 63;
    const int w    = t >> 6;
    const int n0   = bid * 64;

    #pragma unroll
    for (int i = 0; i < 8; ++i) {
        int e = (i * 256 + t) * 8;
        int r = e >> 7, c = e & 127;
        *(u32x4*)&wl[r * LDAP + c] = *(const u32x4*)&Wt[r * D + c];
    }
    #pragma unroll
    for (int i = 0; i < 8; ++i) {
        int idx = i * 256 + t;
        int r = idx >> 5, c4 = idx & 31;
        int gr = n0 + r; if (gr >= N) gr = N - 1;
        float4 v = *(const float4*)&A[(size_t)gr * D + c4 * 4];
        u32 lo = (u32)f2bf(v.x) | ((u32)f2bf(v.y) << 16);
        u32 hi = (u32)f2bf(v.z) | ((u32)f2bf(v.w) << 16);
        *(uint2*)&al[r * LDAP + c4 * 4] = make_uint2(lo, hi);
    }
    __syncthreads();

    const int  fr     = lane & 15;
    const int  kg     = lane >> 4;
    const bool wvalid = (n0 + w * 16) < N;

    f32x4 acc[8];
    #pragma unroll
    for (int i = 0; i < 8; ++i) acc[i] = (f32x4){0.f, 0.f, 0.f, 0.f};

    #pragma unroll
    for (int kk = 0; kk < 4; ++kk) {
        const int ko = kk * 32 + kg * 8;
        s16x8 a = *(const s16x8*)&al[(w * 16 + fr) * LDAP + ko];
        #pragma unroll
        for (int ct = 0; ct < 8; ++ct) {
            s16x8 b = *(const s16x8*)&wl[(ct * 16 + fr) * LDAP + ko];
            acc[ct] = __builtin_amdgcn_mfma_f32_16x16x32_bf16(a, b, acc[ct], 0, 0, 0);
        }
    }
    if (!wvalid) return;

    #pragma unroll
    for (int ct = 0; ct < 8; ++ct) {
        const int c = ct * 16 + fr;
        #pragma unroll
        for (int j = 0; j < 4; ++j) {
            int R = n0 + w * 16 + 4 * kg + j;
            ybf[(size_t)R * D + c] = f2bf(acc[ct][j]);
        }
    }
}

// ---------------------------------------------------------------------------
// pull aggregation -> H bf16. One wave/row, lane owns channels 2l,2l+1.
// Bucket layout: row's records at [row*CAP, row*CAP+min(deg,CAP)).
// 16-deep masked batch (mean degree ~13 -> one serial gather round).
// Overflow rows (deg > CAP) sweep the tiny overflow list (empty in practice).
// ---------------------------------------------------------------------------
__global__ __launch_bounds__(256) void aggregate_kernel(
    const u16* __restrict__ ybf, const u32* __restrict__ counts,
    const u32* __restrict__ packed, const float* __restrict__ wc,
    u32* __restrict__ Hb2, const u32* __restrict__ ovCount,
    const u32* __restrict__ ovRow, const u32* __restrict__ ovRec, int N)
{
    const int lane = threadIdx.x & 63;
    const int row  = blockIdx.x * 4 + (threadIdx.x >> 6);
    if (row >= N) return;

    const float2 wv = ((const float2*)wc)[lane];
    const float2 cv = ((const float2*)(wc + D))[lane];

    const u32 deg = counts[row];
    const u32 beg = (u32)row << 6;
    const u32 end = beg + (deg < (u32)CAP ? deg : (u32)CAP);
    float a0[4] = {0.f, 0.f, 0.f, 0.f};
    float a1[4] = {0.f, 0.f, 0.f, 0.f};

    for (u32 base = beg; base < end; base += 16) {
        u32 p[16], yv[16];
        #pragma unroll
        for (int j = 0; j < 16; ++j) {
            u32 ee = base + j;
            p[j] = packed[ee < end ? ee : end - 1];
        }
        #pragma unroll
        for (int j = 0; j < 16; ++j)
            yv[j] = *(const u32*)(ybf + (size_t)(p[j] & 0xFFFFu) * D + 2 * lane);
        #pragma unroll
        for (int j = 0; j < 16; ++j) {
            float dt = __half2float(__ushort_as_half((u16)(p[j] >> 16)));
            float v0 = fmaxf(0.f, fmaf(dt, wv.x, __uint_as_float(yv[j] << 16)         + cv.x));
            float v1 = fmaxf(0.f, fmaf(dt, wv.y, __uint_as_float(yv[j] & 0xFFFF0000u) + cv.y));
            bool ok = (base + j) < end;
            a0[j & 3] += ok ? v0 : 0.f;
            a1[j & 3] += ok ? v1 : 0.f;
        }
    }
    if (deg > (u32)CAP) {                       // safety net, empty in practice
        u32 ov = *ovCount; if (ov > (u32)OVMAX) ov = (u32)OVMAX;
        for (u32 i = 0; i < ov; ++i) {
            if (ovRow[i] == (u32)row) {
                u32 pr = ovRec[i];
                float dt = __half2float(__ushort_as_half((u16)(pr >> 16)));
                u32 yv = *(const u32*)(ybf + (size_t)(pr & 0xFFFFu) * D + 2 * lane);
                a0[0] += fmaxf(0.f, fmaf(dt, wv.x, __uint_as_float(yv << 16)         + cv.x));
                a1[0] += fmaxf(0.f, fmaf(dt, wv.y, __uint_as_float(yv & 0xFFFF0000u) + cv.y));
            }
        }
    }
    float r0 = (a0[0] + a0[1]) + (a0[2] + a0[3]);
    float r1 = (a1[0] + a1[1]) + (a1[2] + a1[3]);
    Hb2[(size_t)row * 64 + lane] = (u32)f2bf(r0) | ((u32)f2bf(r1) << 16);
}

// ---------------------------------------------------------------------------
// GEMM2: out = f32(Hb @ W2 + x + deg*b2), K=D=128, MFMA 16x16x32 bf16.
// ---------------------------------------------------------------------------
__global__ __launch_bounds__(256) void gemm2_kernel(
    const u16* __restrict__ Asrc, const u16* __restrict__ Wt,
    const float* __restrict__ xres, const u32* __restrict__ degi,
    const float* __restrict__ bvec, float* __restrict__ out, int N)
{
    __shared__ u16 wl[D * LDAP];
    __shared__ u16 al[64 * LDAP];
    const int t    = threadIdx.x;
    const int lane = t & 63;
    const int w    = t >> 6;
    const int n0   = blockIdx.x * 64;

    #pragma unroll
    for (int i = 0; i < 8; ++i) {
        int e = (i * 256 + t) * 8;
        int r = e >> 7, c = e & 127;
        *(u32x4*)&wl[r * LDAP + c] = *(const u32x4*)&Wt[r * D + c];
    }
    #pragma unroll
    for (int i = 0; i < 4; ++i) {
        int idx = i * 256 + t;
        int r = idx >> 4, c8 = idx & 15;
        int gr = n0 + r; if (gr >= N) gr = N - 1;
        *(u32x4*)&al[r * LDAP + c8 * 8] = *(const u32x4*)&Asrc[(size_t)gr * D + c8 * 8];
    }
    __syncthreads();

    const int  fr     = lane & 15;
    const int  kg     = lane >> 4;
    const bool wvalid = (n0 + w * 16) < N;

    f32x4 acc[8];
    #pragma unroll
    for (int i = 0; i < 8; ++i) acc[i] = (f32x4){0.f, 0.f, 0.f, 0.f};

    #pragma unroll
    for (int kk = 0; kk < 4; ++kk) {
        const int ko = kk * 32 + kg * 8;
        s16x8 a = *(const s16x8*)&al[(w * 16 + fr) * LDAP + ko];
        #pragma unroll
        for (int ct = 0; ct < 8; ++ct) {
            s16x8 b = *(const s16x8*)&wl[(ct * 16 + fr) * LDAP + ko];
            acc[ct] = __builtin_amdgcn_mfma_f32_16x16x32_bf16(a, b, acc[ct], 0, 0, 0);
        }
    }
    if (!wvalid) return;

    float degf[4];
    #pragma unroll
    for (int j = 0; j < 4; ++j)
        degf[j] = (float)degi[n0 + w * 16 + 4 * kg + j];
    #pragma unroll
    for (int ct = 0; ct < 8; ++ct) {
        const int c  = ct * 16 + fr;
        const float bv = bvec[c];
        #pragma unroll
        for (int j = 0; j < 4; ++j) {
            int R = n0 + w * 16 + 4 * kg + j;
            float r = acc[ct][j] + xres[(size_t)R * D + c] + degf[j] * bv;
            out[(size_t)R * D + c] = r;
        }
    }
}

// ---------------------------------------------------------------------------
extern "C" void kernel_launch(void* const* d_in, const int* in_sizes, int n_in,
                              void* d_out, int out_size, void* d_ws, size_t ws_size,
                              hipStream_t stream)
{
    const float* x      = (const float*)d_in[0];
    const float* coord  = (const float*)d_in[1];
    const void*  eidx   = d_in[2];
    const float* W_edge = (const float*)d_in[3];
    const float* b_edge = (const float*)d_in[4];
    const float* W1     = (const float*)d_in[5];
    const float* b1     = (const float*)d_in[6];
    const float* W2     = (const float*)d_in[7];
    const float* b2     = (const float*)d_in[8];

    const int N = in_sizes[1] / 3;
    const int E = in_sizes[2] / 2;

    // ---- d_ws: Hb [N*D bf16] | counts [(N+16) u32] | wc [2D f32]
    //            | Wt1 | Wt2 | ovCount | ovRow[OVMAX] | ovRec[OVMAX]
    char* wsb    = (char*)d_ws;
    u16*  Hb     = (u16*)wsb;                 size_t o = (size_t)N * D * 2;
    u32*  counts = (u32*)(wsb + o);           o += (size_t)(N + 16) * 4;
    float* wc    = (float*)(wsb + o);         o += 2 * D * 4 + 64;
    u16*  Wt1    = (u16*)(wsb + o);           o += D * D * 2;
    u16*  Wt2    = (u16*)(wsb + o);           o += D * D * 2;
    u32*  ovCount = (u32*)(wsb + o);          o += 64;
    u32*  ovRow   = (u32*)(wsb + o);          o += OVMAX * 4;
    u32*  ovRec   = (u32*)(wsb + o);

    // ---- d_out scratch: ybf [N*D bf16] | packed [N*CAP u32] (exactly fills
    //      N*D*4 bytes; both dead before the final GEMM overwrites d_out)
    char* ob     = (char*)d_out;
    u16*  ybf    = (u16*)ob;
    u32*  packed = (u32*)(ob + (size_t)N * D * 2);

    const int nz4 = (N + 16 + 3) / 4;
    const int ZB  = (nz4 + 127) / 128;
    prep_zero_kernel<<<D + 1 + ZB, 128, 0, stream>>>(
        W_edge, b_edge, W1, b1, W2, wc, Wt1, Wt2, (u32x4*)counts, nz4, ovCount);

    const int CB = (E + 255) / 256;            // count blocks (1 edge/thread)
    const int GB = (N + 63) / 64;              // gemm blocks
    count_gemm1_kernel<<<CB + GB, 256, 0, stream>>>(
        eidx, coord, counts, packed, ovCount, ovRow, ovRec, E, CB,
        x, Wt1, ybf, N);

    aggregate_kernel<<<(N + 3) / 4, 256, 0, stream>>>(
        ybf, counts, packed, wc, (u32*)Hb, ovCount, ovRow, ovRec, N);

    gemm2_kernel<<<GB, 256, 0, stream>>>(
        Hb, Wt2, x, counts, b2, (float*)d_out, N);
}